// Round 1
// baseline (583.337 us; speedup 1.0000x reference)
//
#include <hip/hip_runtime.h>
#include <math.h>

// Problem constants (from reference)
#define BATCH 1024
#define DIM   512            // K; also fp8 row bytes
#define NCLS  100000
#define SCALE_S 64.0f
#define MARGIN  0.5f
#define EPS_REF 1e-7f
#define SEXP 92.332482616893656878f   // S * log2(e): acc = S*log2e*wf -> exp2(acc)

// Fused-GEMM tiling
#define NSLAB 64             // classes (N) per block; W slab lives in LDS for block lifetime
#define NBLK  1563           // ceil(NCLS/NSLAB)
#define BK    64             // fp8 K-slab bytes per A staging step
#define NKT   8              // DIM/BK
#define MROWS 128            // A rows per m-iteration
#define NMT   8              // BATCH/MROWS

typedef __attribute__((ext_vector_type(4))) float floatx4;

#if __has_builtin(__builtin_amdgcn_exp2f)
#define EXP2(x) __builtin_amdgcn_exp2f(x)
#else
#define EXP2(x) exp2f(x)
#endif

// async global->LDS, 16B per lane; LDS dest = wave-uniform base + lane*16
__device__ __forceinline__ void gload_lds16(const void* g, void* l) {
    __builtin_amdgcn_global_load_lds(
        (const __attribute__((address_space(1))) void*)g,
        (__attribute__((address_space(3))) void*)l, 16, 0, 0);
}

// ---------- prep: per-row ||x||, exact tgt logit, xf8 = fp8(SEXP * x/||x||) ----------
// grid = 1024 blocks, 256 threads (one block per batch row)
__global__ __launch_bounds__(256)
void k_prep(const float* __restrict__ features,
            const float* __restrict__ W,
            const int* __restrict__ y,
            unsigned char* __restrict__ xf8,
            float* __restrict__ rowsum,
            float* __restrict__ tgt) {
    const int row = blockIdx.x;
    const int t = threadIdx.x;
    const int lane = t & 63;
    const int wave = t >> 6;
    __shared__ float redS[4], redD[4];

    const float2 v  = *(const float2*)(features + (size_t)row * DIM + t * 2);
    const float2 wv = *(const float2*)(W + (size_t)y[row] * DIM + t * 2);
    float ss = v.x * v.x + v.y * v.y;
    float dd = v.x * wv.x + v.y * wv.y;
    #pragma unroll
    for (int m = 32; m >= 1; m >>= 1) { ss += __shfl_xor(ss, m); dd += __shfl_xor(dd, m); }
    if (lane == 0) { redS[wave] = ss; redD[wave] = dd; }
    __syncthreads();
    const float tot  = redS[0] + redS[1] + redS[2] + redS[3];
    const float dtot = redD[0] + redD[1] + redD[2] + redD[3];
    const float nrm = fmaxf(sqrtf(tot), 1e-12f);
    const float sc = SEXP / nrm;

    int pk = __builtin_amdgcn_cvt_pk_fp8_f32(v.x * sc, v.y * sc, 0, false);
    *(unsigned short*)(xf8 + (size_t)row * DIM + t * 2) = (unsigned short)(pk & 0xFFFF);

    if (t == 0) { rowsum[row] = 0.0f; tgt[row] = dtot / nrm; }
}

// ---------- fused W-convert + fp8 MFMA GEMM + exp2-sum ----------
// One block per 64-class slab. Phase 1: stream 64x512 fp32 W slab once,
// convert to fp8 in regs, park XOR-swizzled in LDS (32 KB, block lifetime).
// Phase 2: m-loop over 8 x 128 batch rows; A slabs (BK=64) double-buffered
// via global_load_lds with ONE barrier per slab (issue-before-compute).
// Wave tile = 32m x 64n (full n width) -> one atomic per row per block.
__global__ __launch_bounds__(256, 3)
void k_gemm_fused(const float* __restrict__ W,
                  const unsigned char* __restrict__ xf8,
                  float* __restrict__ rowsum) {
    __shared__ __align__(16) unsigned char Ws[NSLAB * DIM];     // 32 KB
    __shared__ __align__(16) unsigned char As[2][MROWS * BK];   // 2 x 8 KB

    const int tid  = threadIdx.x;
    const int wave = tid >> 6;
    const int lane = tid & 63;
    const int quad = lane >> 4;
    const int l15  = lane & 15;
    const int n0   = blockIdx.x * NSLAB;

    // ---- A staging geometry: per round q (2), 16 rows x 64B = 1 KB/wave-issue.
    // LDS dest linear (lane*16); source chunk pre-swizzled (cs ^ (row&3)).
    const int arl = lane >> 2;          // row within 16-row segment
    const int acs = lane & 3;           // 16B chunk within 64B row
    const unsigned char* a_src_base =
        xf8 + (size_t)arl * DIM + ((acs ^ (arl & 3)) << 4);

    // prologue: issue (mt=0, kt=0) into As[0] before W phase (overlaps it)
    #pragma unroll
    for (int q = 0; q < 2; ++q)
        gload_lds16(a_src_base + (size_t)((q * 4 + wave) * 16) * DIM,
                    &As[0][(q * 4 + wave) * 16 * BK]);

    // ---- W fp32 -> fp8 e4m3 (RNE) into LDS, 16B chunks XOR-swizzled by row.
    // 64 rows x 32 chunks = 2048 chunks; 8 per thread; global reads coalesced.
    #pragma unroll
    for (int j = 0; j < 8; ++j) {
        const int c  = j * 256 + tid;
        const int r  = c >> 5;          // 0..63
        const int cs = c & 31;
        int rg = n0 + r; if (rg > NCLS - 1) rg = NCLS - 1;   // tail clamp (masked later)
        const float4* s4 = (const float4*)(W + (size_t)rg * DIM + cs * 16);
        const float4 f0 = s4[0], f1 = s4[1], f2 = s4[2], f3 = s4[3];
        int w0 = __builtin_amdgcn_cvt_pk_fp8_f32(f0.x, f0.y, 0, false);
        w0     = __builtin_amdgcn_cvt_pk_fp8_f32(f0.z, f0.w, w0, true);
        int w1 = __builtin_amdgcn_cvt_pk_fp8_f32(f1.x, f1.y, 0, false);
        w1     = __builtin_amdgcn_cvt_pk_fp8_f32(f1.z, f1.w, w1, true);
        int w2 = __builtin_amdgcn_cvt_pk_fp8_f32(f2.x, f2.y, 0, false);
        w2     = __builtin_amdgcn_cvt_pk_fp8_f32(f2.z, f2.w, w2, true);
        int w3 = __builtin_amdgcn_cvt_pk_fp8_f32(f3.x, f3.y, 0, false);
        w3     = __builtin_amdgcn_cvt_pk_fp8_f32(f3.z, f3.w, w3, true);
        *(int4*)(&Ws[r * DIM + ((cs ^ (r & 7)) << 4)]) = make_int4(w0, w1, w2, w3);
    }

    // ---- fragment LDS byte offsets (kc/kt variants via XOR immediates)
    int aoff[2], boff[4];
    #pragma unroll
    for (int mi = 0; mi < 2; ++mi) {
        const int r = wave * 32 + mi * 16 + l15;
        aoff[mi] = r * BK + (((quad >> 1) ^ (r & 3)) << 4) + ((quad & 1) << 3);
    }
    #pragma unroll
    for (int ni = 0; ni < 4; ++ni) {
        const int r = ni * 16 + l15;
        boff[ni] = r * DIM + (((quad >> 1) ^ (r & 7)) << 4) + ((quad & 1) << 3);
    }

    floatx4 acc[2][4];
    int buf = 0;
    const bool full = (n0 + NSLAB <= NCLS);

    for (int mt = 0; mt < NMT; ++mt) {
        #pragma unroll
        for (int mi = 0; mi < 2; ++mi)
            #pragma unroll
            for (int ni = 0; ni < 4; ++ni)
                acc[mi][ni] = (floatx4){0.f, 0.f, 0.f, 0.f};

        for (int kt = 0; kt < NKT; ++kt) {
            __syncthreads();   // drains prev stage (vmcnt) + W-phase ds_writes on first pass
            // issue NEXT A slab into the other buffer; loads fly under the MFMAs
            const bool last = (kt == NKT - 1);
            if (!last || mt < NMT - 1) {
                const int nmt = last ? mt + 1 : mt;
                const int nkt = last ? 0 : kt + 1;
                #pragma unroll
                for (int q = 0; q < 2; ++q)
                    gload_lds16(a_src_base
                                  + (size_t)(nmt * MROWS + (q * 4 + wave) * 16) * DIM
                                  + nkt * BK,
                                &As[buf ^ 1][(q * 4 + wave) * 16 * BK]);
            }
            #pragma unroll
            for (int kc = 0; kc < 2; ++kc) {
                long a[2], b[4];
                #pragma unroll
                for (int mi = 0; mi < 2; ++mi)
                    a[mi] = *(const long*)(&As[buf][aoff[mi] ^ (kc << 5)]);
                #pragma unroll
                for (int ni = 0; ni < 4; ++ni)
                    b[ni] = *(const long*)(&Ws[boff[ni] ^ (kt << 6) ^ (kc << 5)]);
                #pragma unroll
                for (int mi = 0; mi < 2; ++mi)
                    #pragma unroll
                    for (int ni = 0; ni < 4; ++ni)
                        acc[mi][ni] = __builtin_amdgcn_mfma_f32_16x16x32_fp8_fp8(
                            a[mi], b[ni], acc[mi][ni], 0, 0, 0);
            }
            buf ^= 1;
        }

        // ---- epilogue: acc = S*log2e*wf -> exp2, reduce over n, 1 atomic/row.
        // Overlaps the already-issued (mt+1, kt=0) stage.
        #pragma unroll
        for (int mi = 0; mi < 2; ++mi) {
            #pragma unroll
            for (int reg = 0; reg < 4; ++reg) {
                float p = 0.f;
                if (full) {
                    p = EXP2(acc[mi][0][reg]) + EXP2(acc[mi][1][reg])
                      + EXP2(acc[mi][2][reg]) + EXP2(acc[mi][3][reg]);
                } else {
                    #pragma unroll
                    for (int ni = 0; ni < 4; ++ni) {
                        const int n = n0 + ni * 16 + l15;
                        if (n < NCLS) p += EXP2(acc[mi][ni][reg]);
                    }
                }
                p += __shfl_xor(p, 1);
                p += __shfl_xor(p, 2);
                p += __shfl_xor(p, 4);
                p += __shfl_xor(p, 8);
                if (l15 == 0) {
                    const int m = mt * MROWS + wave * 32 + mi * 16 + quad * 4 + reg;
                    atomicAdd(&rowsum[m], p);
                }
            }
        }
    }
}

// ---------- finalize loss ----------
__global__ void k_finalize(const float* __restrict__ rowsum,
                           const float* __restrict__ tgt,
                           float* __restrict__ out) {
    const int tid = threadIdx.x;
    const int lane = tid & 63;
    const int wave = tid >> 6;
    __shared__ float red[4];

    float s = 0.f;
    #pragma unroll
    for (int i = 0; i < 4; ++i) {
        const int b = tid + i * 256;
        const float traw = tgt[b];
        const float tc = fminf(fmaxf(traw, -1.0f + EPS_REF), 1.0f - EPS_REF);
        const float num = SCALE_S * cosf(acosf(tc) + MARGIN);
        const float excl = rowsum[b] - expf(SCALE_S * traw);
        const float denom = expf(num) + excl;
        s += num - logf(denom);
    }
    #pragma unroll
    for (int m = 32; m >= 1; m >>= 1) s += __shfl_xor(s, m);
    if (lane == 0) red[wave] = s;
    __syncthreads();
    if (tid == 0)
        out[0] = -(red[0] + red[1] + red[2] + red[3]) / (float)BATCH;
}

extern "C" void kernel_launch(void* const* d_in, const int* in_sizes, int n_in,
                              void* d_out, int out_size, void* d_ws, size_t ws_size,
                              hipStream_t stream) {
    const float* features = (const float*)d_in[0];
    const float* W        = (const float*)d_in[1];
    const int*   y        = (const int*)d_in[2];
    float* out = (float*)d_out;

    const size_t XF8_BYTES = (size_t)BATCH * DIM;      // 524,288
    char* ws = (char*)d_ws;
    unsigned char* xf8 = (unsigned char*)ws;
    float* rowsum = (float*)(ws + XF8_BYTES);
    float* tgt    = (float*)(ws + XF8_BYTES + 4096);

    k_prep<<<BATCH, 256, 0, stream>>>(features, W, y, xf8, rowsum, tgt);
    k_gemm_fused<<<NBLK, 256, 0, stream>>>(W, xf8, rowsum);
    k_finalize<<<1, 256, 0, stream>>>(rowsum, tgt, out);
}

// Round 4
// 466.355 us; speedup vs baseline: 1.2508x; 1.2508x over previous
//
#include <hip/hip_runtime.h>
#include <math.h>

// Problem constants (from reference)
#define BATCH 1024
#define DIM   512            // K; also fp8 row bytes
#define NCLS  100000
#define SCALE_S 64.0f
#define MARGIN  0.5f
#define EPS_REF 1e-7f
#define SEXP 92.332482616893656878f   // S * log2(e): acc = S*log2e*wf -> exp2(acc)

// Fused-GEMM tiling
#define NSLAB 64             // classes (N) per block; W slab lives in LDS->regs
#define NBLK  1563           // ceil(NCLS/NSLAB)
#define CHUNK 16             // batch rows per compute chunk
#define NCHUNK_WAVE 16       // chunks per wave: 1024 rows / (16 rows * 4 waves)

typedef __attribute__((ext_vector_type(4))) float floatx4;
typedef __attribute__((ext_vector_type(2))) long  longx2;

#if __has_builtin(__builtin_amdgcn_exp2f)
#define EXP2(x) __builtin_amdgcn_exp2f(x)
#else
#define EXP2(x) exp2f(x)
#endif

// sum within each 16-lane group (harness-proven shfl butterfly; DS pipe is
// otherwise idle in the hot loop, so this overlaps MFMA fine)
__device__ __forceinline__ float red16(float v) {
    v += __shfl_xor(v, 1);
    v += __shfl_xor(v, 2);
    v += __shfl_xor(v, 4);
    v += __shfl_xor(v, 8);
    return v;
}

// ---------- prep: per-row ||x||, exact tgt logit, xf8 in MFMA-fragment order ----------
// xf8 row layout: byte k of the row is stored at quad(k)*128 + kc(k)*8 + (k&7),
// where quad = (k&31)>>3, kc = k>>5. A lane (quad,l15) then reads its full-K
// fragment set as 128 CONTIGUOUS bytes at row*512 + quad*128; the 8-byte word
// at +kk*8 is exactly the A-operand for MFMA step kk (k = kk*32 + quad*8 + b).
__global__ __launch_bounds__(256)
void k_prep(const float* __restrict__ features,
            const float* __restrict__ W,
            const int* __restrict__ y,
            unsigned char* __restrict__ xf8,
            float* __restrict__ rowsum,
            float* __restrict__ tgt) {
    const int row = blockIdx.x;
    const int t = threadIdx.x;
    const int lane = t & 63;
    const int wave = t >> 6;
    __shared__ float redS[4], redD[4];

    const float2 v  = *(const float2*)(features + (size_t)row * DIM + t * 2);
    const float2 wv = *(const float2*)(W + (size_t)y[row] * DIM + t * 2);
    float ss = v.x * v.x + v.y * v.y;
    float dd = v.x * wv.x + v.y * wv.y;
    #pragma unroll
    for (int m = 32; m >= 1; m >>= 1) { ss += __shfl_xor(ss, m); dd += __shfl_xor(dd, m); }
    if (lane == 0) { redS[wave] = ss; redD[wave] = dd; }
    __syncthreads();
    const float tot  = redS[0] + redS[1] + redS[2] + redS[3];
    const float dtot = redD[0] + redD[1] + redD[2] + redD[3];
    const float nrm = fmaxf(sqrtf(tot), 1e-12f);
    const float sc = SEXP / nrm;

    int pk = __builtin_amdgcn_cvt_pk_fp8_f32(v.x * sc, v.y * sc, 0, false);
    const int k0 = t * 2;                       // k0 and k0+1 stay adjacent in frag order
    const int off = ((k0 & 31) >> 3) * 128 + (k0 >> 5) * 8 + (k0 & 7);
    *(unsigned short*)(xf8 + (size_t)row * DIM + off) = (unsigned short)(pk & 0xFFFF);

    if (t == 0) { rowsum[row] = 0.0f; tgt[row] = dtot / nrm; }
}

// ---------- fused W-convert + register-resident fp8 MFMA + exp2-sum ----------
// One block per 64-class slab, 4 waves. Phase 1: stream 64x512 fp32 W slab once,
// convert to fp8, park XOR-swizzled in LDS. Phase 2 (one barrier): each wave
// pulls ALL its B-fragments into 128 VGPRs. Phase 3: loop over this wave's 16
// chunks of 16 batch rows; A fragments double-buffered straight from global
// (xf8 is L2-resident). NO barriers / NO LDS ops in the hot loop.

// epilogue + 64-MFMA body, macro-expanded so all buffer indices are static
#define COMPUTE_CHUNK(Ab, c)                                                   \
    {                                                                          \
        floatx4 acc0 = (floatx4){0.f,0.f,0.f,0.f};                             \
        floatx4 acc1 = (floatx4){0.f,0.f,0.f,0.f};                             \
        floatx4 acc2 = (floatx4){0.f,0.f,0.f,0.f};                             \
        floatx4 acc3 = (floatx4){0.f,0.f,0.f,0.f};                             \
        _Pragma("unroll")                                                      \
        for (int kk = 0; kk < 16; ++kk) {                                      \
            const long av = (kk & 1) ? Ab[kk >> 1][1] : Ab[kk >> 1][0];        \
            acc0 = __builtin_amdgcn_mfma_f32_16x16x32_fp8_fp8(av, Bf[0][kk], acc0, 0, 0, 0); \
            acc1 = __builtin_amdgcn_mfma_f32_16x16x32_fp8_fp8(av, Bf[1][kk], acc1, 0, 0, 0); \
            acc2 = __builtin_amdgcn_mfma_f32_16x16x32_fp8_fp8(av, Bf[2][kk], acc2, 0, 0, 0); \
            acc3 = __builtin_amdgcn_mfma_f32_16x16x32_fp8_fp8(av, Bf[3][kk], acc3, 0, 0, 0); \
        }                                                                      \
        const int rowb = (wave * NCHUNK_WAVE + (c)) * CHUNK + quad * 4;        \
        _Pragma("unroll")                                                      \
        for (int reg = 0; reg < 4; ++reg) {                                    \
            float p;                                                           \
            if (full) {                                                        \
                p = EXP2(acc0[reg]) + EXP2(acc1[reg])                          \
                  + EXP2(acc2[reg]) + EXP2(acc3[reg]);                         \
            } else {                                                           \
                p = 0.f;                                                       \
                if (n0 +      l15 < NCLS) p += EXP2(acc0[reg]);                \
                if (n0 + 16 + l15 < NCLS) p += EXP2(acc1[reg]);                \
                if (n0 + 32 + l15 < NCLS) p += EXP2(acc2[reg]);                \
                if (n0 + 48 + l15 < NCLS) p += EXP2(acc3[reg]);                \
            }                                                                  \
            p = red16(p);                                                      \
            if (l15 == 0) atomicAdd(&rowsum[rowb + reg], p);                   \
        }                                                                      \
    }

__global__ __launch_bounds__(256, 2)
void k_gemm_fused(const float* __restrict__ W,
                  const unsigned char* __restrict__ xf8,
                  float* __restrict__ rowsum) {
    __shared__ __align__(16) unsigned char Ws[NSLAB * DIM];     // 32 KB

    const int tid  = threadIdx.x;
    const int wave = tid >> 6;
    const int lane = tid & 63;
    const int quad = lane >> 4;
    const int l15  = lane & 15;
    const int n0   = blockIdx.x * NSLAB;

    // ---- Phase 1: W fp32 -> fp8 e4m3 (RNE) into LDS, 16B chunks XOR-swizzled by row
    #pragma unroll
    for (int j = 0; j < 8; ++j) {
        const int c  = j * 256 + tid;
        const int r  = c >> 5;          // 0..63
        const int cs = c & 31;
        int rg = n0 + r; if (rg > NCLS - 1) rg = NCLS - 1;   // tail clamp (masked later)
        const float4* s4 = (const float4*)(W + (size_t)rg * DIM + cs * 16);
        const float4 f0 = s4[0], f1 = s4[1], f2 = s4[2], f3 = s4[3];
        int w0 = __builtin_amdgcn_cvt_pk_fp8_f32(f0.x, f0.y, 0, false);
        w0     = __builtin_amdgcn_cvt_pk_fp8_f32(f0.z, f0.w, w0, true);
        int w1 = __builtin_amdgcn_cvt_pk_fp8_f32(f1.x, f1.y, 0, false);
        w1     = __builtin_amdgcn_cvt_pk_fp8_f32(f1.z, f1.w, w1, true);
        int w2 = __builtin_amdgcn_cvt_pk_fp8_f32(f2.x, f2.y, 0, false);
        w2     = __builtin_amdgcn_cvt_pk_fp8_f32(f2.z, f2.w, w2, true);
        int w3 = __builtin_amdgcn_cvt_pk_fp8_f32(f3.x, f3.y, 0, false);
        w3     = __builtin_amdgcn_cvt_pk_fp8_f32(f3.z, f3.w, w3, true);
        *(int4*)(&Ws[r * DIM + ((cs ^ (r & 7)) << 4)]) = make_int4(w0, w1, w2, w3);
    }
    __syncthreads();

    // ---- Phase 2: all B fragments for this wave's full 64n x 512K tile -> 128 VGPRs
    long Bf[4][16];
    #pragma unroll
    for (int ni = 0; ni < 4; ++ni) {
        const int r = ni * 16 + l15;
        #pragma unroll
        for (int kk = 0; kk < 16; ++kk) {
            const int cs = kk * 2 + (quad >> 1);
            Bf[ni][kk] = *(const long*)(&Ws[r * DIM + ((cs ^ (r & 7)) << 4) + ((quad & 1) << 3)]);
        }
    }

    const bool full = (n0 + NSLAB <= NCLS);

    // ---- Phase 3: chunk loop, A from global (fragment-order xf8), double-buffered
    const unsigned char* abase =
        xf8 + (size_t)(wave * NCHUNK_WAVE * CHUNK + l15) * DIM + quad * 128;

    longx2 A0[8], A1[8];
    #pragma unroll
    for (int j2 = 0; j2 < 8; ++j2)
        A0[j2] = *(const longx2*)(abase + j2 * 16);

    for (int c = 0; c < NCHUNK_WAVE; c += 2) {
        #pragma unroll
        for (int j2 = 0; j2 < 8; ++j2)
            A1[j2] = *(const longx2*)(abase + (size_t)(c + 1) * (CHUNK * DIM) + j2 * 16);
        COMPUTE_CHUNK(A0, c)
        const int cn = (c + 2 < NCHUNK_WAVE) ? c + 2 : 0;   // last prefetch harmless
        #pragma unroll
        for (int j2 = 0; j2 < 8; ++j2)
            A0[j2] = *(const longx2*)(abase + (size_t)cn * (CHUNK * DIM) + j2 * 16);
        COMPUTE_CHUNK(A1, c + 1)
    }
}

// ---------- finalize loss ----------
__global__ void k_finalize(const float* __restrict__ rowsum,
                           const float* __restrict__ tgt,
                           float* __restrict__ out) {
    const int tid = threadIdx.x;
    const int lane = tid & 63;
    const int wave = tid >> 6;
    __shared__ float red[4];

    float s = 0.f;
    #pragma unroll
    for (int i = 0; i < 4; ++i) {
        const int b = tid + i * 256;
        const float traw = tgt[b];
        const float tc = fminf(fmaxf(traw, -1.0f + EPS_REF), 1.0f - EPS_REF);
        const float num = SCALE_S * cosf(acosf(tc) + MARGIN);
        const float excl = rowsum[b] - expf(SCALE_S * traw);
        const float denom = expf(num) + excl;
        s += num - logf(denom);
    }
    #pragma unroll
    for (int m = 32; m >= 1; m >>= 1) s += __shfl_xor(s, m);
    if (lane == 0) red[wave] = s;
    __syncthreads();
    if (tid == 0)
        out[0] = -(red[0] + red[1] + red[2] + red[3]) / (float)BATCH;
}

extern "C" void kernel_launch(void* const* d_in, const int* in_sizes, int n_in,
                              void* d_out, int out_size, void* d_ws, size_t ws_size,
                              hipStream_t stream) {
    const float* features = (const float*)d_in[0];
    const float* W        = (const float*)d_in[1];
    const int*   y        = (const int*)d_in[2];
    float* out = (float*)d_out;

    const size_t XF8_BYTES = (size_t)BATCH * DIM;      // 524,288
    char* ws = (char*)d_ws;
    unsigned char* xf8 = (unsigned char*)ws;
    float* rowsum = (float*)(ws + XF8_BYTES);
    float* tgt    = (float*)(ws + XF8_BYTES + 4096);

    k_prep<<<BATCH, 256, 0, stream>>>(features, W, y, xf8, rowsum, tgt);
    k_gemm_fused<<<NBLK, 256, 0, stream>>>(W, xf8, rowsum);
    k_finalize<<<1, 256, 0, stream>>>(rowsum, tgt, out);
}

// Round 5
// 396.402 us; speedup vs baseline: 1.4716x; 1.1765x over previous
//
#include <hip/hip_runtime.h>
#include <math.h>

// Problem constants (from reference)
#define BATCH 1024
#define DIM   512            // K; also fp8 row bytes
#define NCLS  100000
#define SCALE_S 64.0f
#define MARGIN  0.5f
#define EPS_REF 1e-7f
#define SEXP 92.332482616893656878f   // S * log2(e): acc = S*log2e*wf -> exp2(acc)

// Fused-GEMM tiling
#define NSLAB 64             // classes (N) per block; W slab -> LDS -> regs
#define NBLK  1563           // ceil(NCLS/NSLAB)
#define CHUNK 16             // batch rows per compute chunk
#define NCHUNK_WAVE 16       // chunks per wave: 1024 rows / (16 rows * 4 waves)
#define NRSCOPY 8            // rowsum replicas (atomic line-contention /8, XCD-aligned)

typedef __attribute__((ext_vector_type(4))) float floatx4;
typedef __attribute__((ext_vector_type(2))) long  longx2;

#if __has_builtin(__builtin_amdgcn_exp2f)
#define EXP2(x) __builtin_amdgcn_exp2f(x)
#else
#define EXP2(x) exp2f(x)
#endif

// sum within each 16-lane group
__device__ __forceinline__ float red16(float v) {
    v += __shfl_xor(v, 1);
    v += __shfl_xor(v, 2);
    v += __shfl_xor(v, 4);
    v += __shfl_xor(v, 8);
    return v;
}

// ---------- prep: per-row ||x||, exact tgt logit, xf8 in MFMA-fragment order ----------
// xf8 row layout: byte k stored at quad(k)*128 + kc(k)*8 + (k&7), quad=(k&31)>>3,
// kc=k>>5. Lane (quad,l15) reads its full-K A-fragment set as 128 contiguous
// bytes at row*512 + quad*128; 8B word at +kk*8 is the A-operand for MFMA step kk.
__global__ __launch_bounds__(256)
void k_prep(const float* __restrict__ features,
            const float* __restrict__ W,
            const int* __restrict__ y,
            unsigned char* __restrict__ xf8,
            float* __restrict__ rowsum,
            float* __restrict__ tgt) {
    const int row = blockIdx.x;
    const int t = threadIdx.x;
    const int lane = t & 63;
    const int wave = t >> 6;
    __shared__ float redS[4], redD[4];

    const float2 v  = *(const float2*)(features + (size_t)row * DIM + t * 2);
    const float2 wv = *(const float2*)(W + (size_t)y[row] * DIM + t * 2);
    float ss = v.x * v.x + v.y * v.y;
    float dd = v.x * wv.x + v.y * wv.y;
    #pragma unroll
    for (int m = 32; m >= 1; m >>= 1) { ss += __shfl_xor(ss, m); dd += __shfl_xor(dd, m); }
    if (lane == 0) { redS[wave] = ss; redD[wave] = dd; }
    __syncthreads();
    const float tot  = redS[0] + redS[1] + redS[2] + redS[3];
    const float dtot = redD[0] + redD[1] + redD[2] + redD[3];
    const float nrm = fmaxf(sqrtf(tot), 1e-12f);
    const float sc = SEXP / nrm;

    int pk = __builtin_amdgcn_cvt_pk_fp8_f32(v.x * sc, v.y * sc, 0, false);
    const int k0 = t * 2;                       // k0,k0+1 adjacent in frag order
    const int off = ((k0 & 31) >> 3) * 128 + (k0 >> 5) * 8 + (k0 & 7);
    *(unsigned short*)(xf8 + (size_t)row * DIM + off) = (unsigned short)(pk & 0xFFFF);

    if (t < NRSCOPY) rowsum[t * BATCH + row] = 0.0f;
    if (t == 0) tgt[row] = dtot / nrm;
}

// ---------- fused W-convert + register-resident fp8 MFMA + exp2-sum ----------
// ALL hot-array indices are textual literals (macros) so SROA promotes
// Bf[64 longs] / A0,A1[8 longx2] / acc to VGPRs (round-4 lesson: pragma-unroll
// indices are runtime at SROA time -> alloca stayed in scratch, VGPR=100).

#define LBK(ni,kk) { const int r_ = (ni)*16 + l15;                             \
    const int cs_ = (kk)*2 + qh;                                               \
    Bf[ni][kk] = *(const long*)(&Ws[r_*DIM + (((cs_)^(r_&7))<<4) + ql8]); }

#define LB16(ni) LBK(ni,0) LBK(ni,1) LBK(ni,2)  LBK(ni,3)  LBK(ni,4)  LBK(ni,5)  LBK(ni,6)  LBK(ni,7) \
                 LBK(ni,8) LBK(ni,9) LBK(ni,10) LBK(ni,11) LBK(ni,12) LBK(ni,13) LBK(ni,14) LBK(ni,15)

#define LA(Ab, c) { const unsigned char* p_ = abase + (size_t)(c) * (CHUNK * DIM); \
    Ab[0] = *(const longx2*)(p_ +  0); Ab[1] = *(const longx2*)(p_ + 16);      \
    Ab[2] = *(const longx2*)(p_ + 32); Ab[3] = *(const longx2*)(p_ + 48);      \
    Ab[4] = *(const longx2*)(p_ + 64); Ab[5] = *(const longx2*)(p_ + 80);      \
    Ab[6] = *(const longx2*)(p_ + 96); Ab[7] = *(const longx2*)(p_ + 112); }

#define STEP(Ab, kk) { const long av_ = Ab[(kk)>>1][(kk)&1];                   \
    acc0 = __builtin_amdgcn_mfma_f32_16x16x32_fp8_fp8(av_, Bf[0][kk], acc0, 0, 0, 0); \
    acc1 = __builtin_amdgcn_mfma_f32_16x16x32_fp8_fp8(av_, Bf[1][kk], acc1, 0, 0, 0); \
    acc2 = __builtin_amdgcn_mfma_f32_16x16x32_fp8_fp8(av_, Bf[2][kk], acc2, 0, 0, 0); \
    acc3 = __builtin_amdgcn_mfma_f32_16x16x32_fp8_fp8(av_, Bf[3][kk], acc3, 0, 0, 0); }

#define EPI(reg) { float p_;                                                   \
    if (full) { p_ = EXP2(acc0[reg]) + EXP2(acc1[reg])                         \
                   + EXP2(acc2[reg]) + EXP2(acc3[reg]); }                      \
    else { p_ = 0.f;                                                           \
        if (n0 +      l15 < NCLS) p_ += EXP2(acc0[reg]);                       \
        if (n0 + 16 + l15 < NCLS) p_ += EXP2(acc1[reg]);                       \
        if (n0 + 32 + l15 < NCLS) p_ += EXP2(acc2[reg]);                       \
        if (n0 + 48 + l15 < NCLS) p_ += EXP2(acc3[reg]); }                     \
    p_ = red16(p_);                                                            \
    if (l15 == 0) atomicAdd(&rs[rowb_ + (reg)], p_); }

#define COMPUTE(Ab, c) {                                                       \
    floatx4 acc0 = (floatx4){0.f,0.f,0.f,0.f};                                 \
    floatx4 acc1 = (floatx4){0.f,0.f,0.f,0.f};                                 \
    floatx4 acc2 = (floatx4){0.f,0.f,0.f,0.f};                                 \
    floatx4 acc3 = (floatx4){0.f,0.f,0.f,0.f};                                 \
    STEP(Ab,0)  STEP(Ab,1)  STEP(Ab,2)  STEP(Ab,3)                             \
    STEP(Ab,4)  STEP(Ab,5)  STEP(Ab,6)  STEP(Ab,7)                             \
    STEP(Ab,8)  STEP(Ab,9)  STEP(Ab,10) STEP(Ab,11)                            \
    STEP(Ab,12) STEP(Ab,13) STEP(Ab,14) STEP(Ab,15)                            \
    const int rowb_ = (wave * NCHUNK_WAVE + (c)) * CHUNK + quad * 4;           \
    EPI(0) EPI(1) EPI(2) EPI(3) }

__global__ __launch_bounds__(256, 2)
void k_gemm_fused(const float* __restrict__ W,
                  const unsigned char* __restrict__ xf8,
                  float* __restrict__ rowsum) {
    __shared__ __align__(16) unsigned char Ws[NSLAB * DIM];     // 32 KB

    const int tid  = threadIdx.x;
    const int wave = tid >> 6;
    const int lane = tid & 63;
    const int quad = lane >> 4;
    const int l15  = lane & 15;
    const int qh   = quad >> 1;
    const int ql8  = (quad & 1) << 3;
    const int n0   = blockIdx.x * NSLAB;
    float* rs = rowsum + (blockIdx.x & (NRSCOPY - 1)) * BATCH;

    // A chunk base for this lane (fragment-order xf8)
    const unsigned char* abase =
        xf8 + (size_t)(wave * NCHUNK_WAVE * CHUNK + l15) * DIM + quad * 128;

    // prefetch chunk 0 while Phase 1 streams W
    longx2 A0[8], A1[8];
    LA(A0, 0)

    // ---- Phase 1: W fp32 -> fp8 e4m3 (RNE) into LDS, 16B chunks XOR-swizzled
    #pragma unroll
    for (int j = 0; j < 8; ++j) {
        const int c  = j * 256 + tid;
        const int r  = c >> 5;          // 0..63
        const int cs = c & 31;
        int rg = n0 + r; if (rg > NCLS - 1) rg = NCLS - 1;   // tail clamp (masked later)
        const float4* s4 = (const float4*)(W + (size_t)rg * DIM + cs * 16);
        const float4 f0 = s4[0], f1 = s4[1], f2 = s4[2], f3 = s4[3];
        int w0 = __builtin_amdgcn_cvt_pk_fp8_f32(f0.x, f0.y, 0, false);
        w0     = __builtin_amdgcn_cvt_pk_fp8_f32(f0.z, f0.w, w0, true);
        int w1 = __builtin_amdgcn_cvt_pk_fp8_f32(f1.x, f1.y, 0, false);
        w1     = __builtin_amdgcn_cvt_pk_fp8_f32(f1.z, f1.w, w1, true);
        int w2 = __builtin_amdgcn_cvt_pk_fp8_f32(f2.x, f2.y, 0, false);
        w2     = __builtin_amdgcn_cvt_pk_fp8_f32(f2.z, f2.w, w2, true);
        int w3 = __builtin_amdgcn_cvt_pk_fp8_f32(f3.x, f3.y, 0, false);
        w3     = __builtin_amdgcn_cvt_pk_fp8_f32(f3.z, f3.w, w3, true);
        *(int4*)(&Ws[r * DIM + ((cs ^ (r & 7)) << 4)]) = make_int4(w0, w1, w2, w3);
    }
    __syncthreads();

    // ---- Phase 2: B fragments (64n x K=512) -> 128 VGPRs, literal indices
    long Bf[4][16];
    LB16(0) LB16(1) LB16(2) LB16(3)

    const bool full = (n0 + NSLAB <= NCLS);

    // ---- Phase 3: chunk loop, A from global (L2-hot), double-buffered,
    // no barriers / no LDS ops
    #pragma unroll 1
    for (int c = 0; c < NCHUNK_WAVE; c += 2) {
        LA(A1, c + 1)
        COMPUTE(A0, c)
        const int cn = (c + 2 < NCHUNK_WAVE) ? c + 2 : 0;   // last prefetch harmless
        LA(A0, cn)
        COMPUTE(A1, c + 1)
    }
}

// ---------- finalize loss ----------
__global__ void k_finalize(const float* __restrict__ rowsum,
                           const float* __restrict__ tgt,
                           float* __restrict__ out) {
    const int tid = threadIdx.x;
    const int lane = tid & 63;
    const int wave = tid >> 6;
    __shared__ float red[4];

    float s = 0.f;
    #pragma unroll
    for (int i = 0; i < 4; ++i) {
        const int b = tid + i * 256;
        float rsum = 0.f;
        #pragma unroll
        for (int cp = 0; cp < NRSCOPY; ++cp) rsum += rowsum[cp * BATCH + b];
        const float traw = tgt[b];
        const float tc = fminf(fmaxf(traw, -1.0f + EPS_REF), 1.0f - EPS_REF);
        const float num = SCALE_S * cosf(acosf(tc) + MARGIN);
        const float excl = rsum - expf(SCALE_S * traw);
        const float denom = expf(num) + excl;
        s += num - logf(denom);
    }
    #pragma unroll
    for (int m = 32; m >= 1; m >>= 1) s += __shfl_xor(s, m);
    if (lane == 0) red[wave] = s;
    __syncthreads();
    if (tid == 0)
        out[0] = -(red[0] + red[1] + red[2] + red[3]) / (float)BATCH;
}

extern "C" void kernel_launch(void* const* d_in, const int* in_sizes, int n_in,
                              void* d_out, int out_size, void* d_ws, size_t ws_size,
                              hipStream_t stream) {
    const float* features = (const float*)d_in[0];
    const float* W        = (const float*)d_in[1];
    const int*   y        = (const int*)d_in[2];
    float* out = (float*)d_out;

    const size_t XF8_BYTES = (size_t)BATCH * DIM;      // 524,288
    const size_t RS_BYTES  = (size_t)NRSCOPY * BATCH * sizeof(float);   // 32 KB
    char* ws = (char*)d_ws;
    unsigned char* xf8 = (unsigned char*)ws;
    float* rowsum = (float*)(ws + XF8_BYTES);
    float* tgt    = (float*)(ws + XF8_BYTES + RS_BYTES);

    k_prep<<<BATCH, 256, 0, stream>>>(features, W, y, xf8, rowsum, tgt);
    k_gemm_fused<<<NBLK, 256, 0, stream>>>(W, xf8, rowsum);
    k_finalize<<<1, 256, 0, stream>>>(rowsum, tgt, out);
}